// Round 2
// baseline (71.646 us; speedup 1.0000x reference)
//
#include <hip/hip_runtime.h>

#define N_AGENTS 8192
#define BLOCK    512
#define APB      32                    // agents per block
#define CHUNKS   (BLOCK / APB)         // 16 goal chunks (one per 32-thread group)
#define GPC      (N_AGENTS / CHUNKS)   // 512 goals per chunk

__global__ __launch_bounds__(BLOCK)
void rollout_policy_kernel(const float* __restrict__ X,
                           const float* __restrict__ U,
                           int* __restrict__ out)
{
    // goals staged as (gx, gy) pairs: 8192 * 8B = 64 KB LDS
    __shared__ __align__(16) float2 gShared[N_AGENTS];
    __shared__ float sBest[CHUNKS][APB];
    __shared__ int   sIdx[CHUNKS][APB];

    const int tid    = threadIdx.x;
    const int b      = blockIdx.x;
    const int aLocal = tid & (APB - 1);
    const int chunk  = tid >> 5;              // tid / APB
    const int a      = b * APB + aLocal;

    // ---- stage all goals into LDS (goal g lives at row 8192+g, stride-3) ----
    const float* gp = X + 3 * N_AGENTS;
    #pragma unroll
    for (int g = tid; g < N_AGENTS; g += BLOCK) {
        gShared[g] = make_float2(gp[3 * g], gp[3 * g + 1]);
    }

    const float ax = X[3 * a];
    const float ay = X[3 * a + 1];
    __syncthreads();

    // ---- per-thread argmin over this thread's goal chunk (in-order, strict <) ----
    float best = 1e30f;
    int   bidx = 0;
    const int g0 = chunk * GPC;
    #pragma unroll 8
    for (int j = 0; j < GPC; j += 2) {
        // 16B-aligned: (g0 + j) is even -> byte offset multiple of 16
        float4 gg = *reinterpret_cast<const float4*>(&gShared[g0 + j]);
        float d0 = fabsf(ax - gg.x) + fabsf(ay - gg.y);
        float d1 = fabsf(ax - gg.z) + fabsf(ay - gg.w);
        // pair-reduce first (keeps first-index tie-break: strict <), then merge
        float dmin = fminf(d0, d1);
        int   imin = (d1 < d0) ? (g0 + j + 1) : (g0 + j);
        if (dmin < best) { best = dmin; bidx = imin; }
    }
    sBest[chunk][aLocal] = best;
    sIdx [chunk][aLocal] = bidx;
    __syncthreads();

    // ---- merge the 16 chunk-partials per agent (ascending chunk order keeps
    //      first-index tie-break = jnp.argmin semantics) + fused policy tail ----
    if (tid < APB) {
        float bb = sBest[0][tid];
        int   bi = sIdx [0][tid];
        #pragma unroll
        for (int c = 1; c < CHUNKS; ++c) {
            float v = sBest[c][tid];
            if (v < bb) { bb = v; bi = sIdx[c][tid]; }
        }
        // thread tid (<32) owns agent b*APB+tid == its own (ax, ay)
        float2 g  = gShared[bi];
        float  dx = g.x - ax;
        float  dy = g.y - ay;

        float p0 = dx > 0.0f ? 1.0f : 0.0f;
        float p1 = dx < 0.0f ? 1.0f : 0.0f;
        float p2 = dy > 0.0f ? 1.0f : 0.0f;
        float p3 = dy < 0.0f ? 1.0f : 0.0f;
        float p4 = (dx == 0.0f && dy == 0.0f) ? 1.0f : 0.0f;

        float c0 = p0;
        float c1 = c0 + p1;
        float c2 = c1 + p2;
        float c3 = c2 + p3;
        float c4 = c3 + p4;

        float t = U[b * APB + tid] * c4;
        int action = (c0 >= t) ? 0
                   : (c1 >= t) ? 1
                   : (c2 >= t) ? 2
                   : (c3 >= t) ? 3
                   : 4;
        out[b * APB + tid] = action;
    }
}

extern "C" void kernel_launch(void* const* d_in, const int* in_sizes, int n_in,
                              void* d_out, int out_size, void* d_ws, size_t ws_size,
                              hipStream_t stream)
{
    const float* X = (const float*)d_in[0];   // (16384, 3) f32
    const float* U = (const float*)d_in[1];   // (8192,)    f32
    int* out = (int*)d_out;                   // (8192,)    i32

    dim3 grid(N_AGENTS / APB);   // 256 blocks -> ~1 per CU
    dim3 block(BLOCK);
    rollout_policy_kernel<<<grid, block, 0, stream>>>(X, U, out);
}